// Round 8
// baseline (10257.790 us; speedup 1.0000x reference)
//
#include <hip/hip_runtime.h>
#include <hip/hip_bf16.h>
#include <math.h>

// EncoderRNN on MI355X. Inputs fp32, OUTPUT FP32 (reference dtype — the
// "(bf16, ...)" in the harness error label is unconditional text; rounds 5-7
// failed identically because bf16 was written into the fp32 out buffer).
//   k_uw:     u = Wsi^T vs, w = Wsh^T vs, cbd = b_bd.vs     (fp64 accum)
//   k_wsplit: W1ih,W1hh -> bf16 hi+lo ; W2ih,W2hh -> bf16 hi
//   scan k=0..64; every 8 steps: k_embed (v chunk, fp32) + k_zx (fp64)
//     G_k: RA_x = v_k@W1ih^T (3-pass hi/lo staged from fp32 v)
//          RA_h = h1r1@W1hh^T (3-pass)  [h1r1 = (1-s_{k-1}) h1raw, pre-masked]
//          RB_x = h1r2@W2ih_h^T (2-pass) [h1r2 = s_{k-1} h1raw]
//          RB_h = h2@W2hh_h^T (2-pass)
//     E_k: s_k = (sigm(zx[k]+rdm_{k-1}) > 0.5); lstm1_k -> craw,h1r1,h1r2,rdm_k;
//          lstm2_{k-1} -> c2,h2; k==64 -> d_out = fp32(h2)
// Guards (fp32 diag): 10000+i bad in_sizes; 9998 bad out_size; 100+MB ws small.

typedef __attribute__((ext_vector_type(8))) short short8;
typedef __attribute__((ext_vector_type(4))) short short4v;
typedef __attribute__((ext_vector_type(4))) float f32x4;
typedef __hip_bfloat16 bf16;

__device__ __forceinline__ float sigm(float x) { return 1.0f / (1.0f + expf(-x)); }
__device__ __forceinline__ short bfbits(float x) {
  bf16 h = __float2bfloat16(x);
  return __builtin_bit_cast(short, h);
}
// fp32 -> 8 bf16 (mode 0: hi, mode 1: residual lo)
__device__ __forceinline__ short8 cvt8(const float* __restrict__ p, int mode)
{
  f32x4 a = *(const f32x4*)p;
  f32x4 b = *(const f32x4*)(p + 4);
  short8 r;
#pragma unroll
  for (int j = 0; j < 8; ++j) {
    float x = (j < 4) ? a[j] : b[j - 4];
    if (mode) {
      bf16 h = __float2bfloat16(x);
      x = x - __bfloat162float(h);
    }
    r[j] = bfbits(x);
  }
  return r;
}

// ---------------------------------------------------------------------------
// 128x128 GEMM tile: C += A(128xK) * B(128xK)^T, K = nChunks*64, fp32 acc.
// A source: fp32 (cvt to bf16 hi/lo per amode) if Af32 != null, else bf16.
// Double-buffered XOR-swizzled LDS; 16x16x32 bf16 MFMA; 2x2 waves of 64x64.
// ---------------------------------------------------------------------------
__device__ __forceinline__ void gemm_core(
    const float* __restrict__ Af32, const bf16* __restrict__ Abf,
    int lda, int amode,
    const bf16* __restrict__ B, int ldb,
    int nChunks, short* ls, f32x4 acc[4][4])
{
  const int tid  = threadIdx.x;
  const int lane = tid & 63;
  const int wave = tid >> 6;
  const int wr = (wave & 1) * 64;
  const int wc = (wave >> 1) * 64;
  const int m  = lane & 15;
  const int kg = lane >> 4;

  int srow[4], sseg[4], ssw[4];
#pragma unroll
  for (int i = 0; i < 4; ++i) {
    int linear = i * 256 + tid;
    srow[i] = linear >> 3;
    sseg[i] = linear & 7;
    ssw[i]  = (sseg[i] ^ (srow[i] & 7)) * 8;
  }

  short8 areg[4], breg[4];
#pragma unroll
  for (int i = 0; i < 4; ++i) {
    if (Af32) areg[i] = cvt8(Af32 + (size_t)srow[i] * lda + sseg[i] * 8, amode);
    else      areg[i] = *(const short8*)(Abf + (size_t)srow[i] * lda + sseg[i] * 8);
    breg[i] = *(const short8*)(B + (size_t)srow[i] * ldb + sseg[i] * 8);
  }
#pragma unroll
  for (int i = 0; i < 4; ++i) {
    *(short8*)(ls + srow[i] * 64 + ssw[i])        = areg[i];
    *(short8*)(ls + 8192 + srow[i] * 64 + ssw[i]) = breg[i];
  }
  __syncthreads();

  for (int c = 0; c < nChunks; ++c) {
    if (c + 1 < nChunks) {
#pragma unroll
      for (int i = 0; i < 4; ++i) {
        if (Af32) areg[i] = cvt8(Af32 + (size_t)srow[i] * lda + (c + 1) * 64 + sseg[i] * 8, amode);
        else      areg[i] = *(const short8*)(Abf + (size_t)srow[i] * lda + (c + 1) * 64 + sseg[i] * 8);
        breg[i] = *(const short8*)(B + (size_t)srow[i] * ldb + (c + 1) * 64 + sseg[i] * 8);
      }
    }
    const short* la = ls + (c & 1) * 16384;
    const short* lb = la + 8192;
#pragma unroll
    for (int ks = 0; ks < 2; ++ks) {
      short8 af[4], bfr[4];
#pragma unroll
      for (int f = 0; f < 4; ++f) {
        int ar = wr + f * 16 + m;
        af[f]  = *(const short8*)(la + ar * 64 + (((ks * 4 + kg) ^ (ar & 7)) * 8));
        int br = wc + f * 16 + m;
        bfr[f] = *(const short8*)(lb + br * 64 + (((ks * 4 + kg) ^ (br & 7)) * 8));
      }
#pragma unroll
      for (int fr = 0; fr < 4; ++fr)
#pragma unroll
        for (int fc = 0; fc < 4; ++fc)
          acc[fr][fc] = __builtin_amdgcn_mfma_f32_16x16x32_bf16(af[fr], bfr[fc], acc[fr][fc], 0, 0, 0);
    }
    if (c + 1 < nChunks) {
      short* lw = ls + ((c + 1) & 1) * 16384;
#pragma unroll
      for (int i = 0; i < 4; ++i) {
        *(short8*)(lw + srow[i] * 64 + ssw[i])        = areg[i];
        *(short8*)(lw + 8192 + srow[i] * 64 + ssw[i]) = breg[i];
      }
    }
    __syncthreads();
  }
}

// C/D frag layout (m89/m91-verified): col = lane&15, row = (lane>>4)*4 + reg.
template <typename F>
__device__ __forceinline__ void epilogue(const f32x4 acc[4][4], F&& body)
{
  const int tid = threadIdx.x, lane = tid & 63, wave = tid >> 6;
  const int m = lane & 15, kg = lane >> 4;
  const int wr = (wave & 1) * 64, wc = (wave >> 1) * 64;
#pragma unroll
  for (int fr = 0; fr < 4; ++fr)
#pragma unroll
    for (int fc = 0; fc < 4; ++fc)
#pragma unroll
      for (int r = 0; r < 4; ++r)
        body(wr + fr * 16 + kg * 4 + r, wc + fc * 16 + m, acc[fr][fc][r]);
}

// ---------------------------------------------------------------------------
__global__ void k_diag(float* __restrict__ out, float val)
{
  if (threadIdx.x == 0 && blockIdx.x == 0) out[0] = val;
}

// u[h]=sum_m vs[m]*Wsi[m,h]; w[h]=sum_m vs[m]*Wsh[m,h]; cbd=b_bd.vs  (fp64)
__global__ void k_uw(const float* __restrict__ Wsi, const float* __restrict__ Wsh,
                     const float* __restrict__ bbd, const float* __restrict__ vs,
                     double* __restrict__ u, double* __restrict__ wv,
                     double* __restrict__ cbdp)
{
  const int blk = blockIdx.x;
  if (blk < 8) {
    const float* W = (blk < 4) ? Wsi : Wsh;
    double* out = (blk < 4) ? u : wv;
    int h = (blk & 3) * 256 + threadIdx.x;
    double a = 0.0;
    for (int mm = 0; mm < 512; ++mm)
      a += (double)vs[mm] * (double)W[mm * 1024 + h];
    out[h] = a;
  } else if (threadIdx.x < 64) {
    double a = 0.0;
    for (int mm = threadIdx.x; mm < 512; mm += 64)
      a += (double)vs[mm] * (double)bbd[mm];
#pragma unroll
    for (int o = 32; o > 0; o >>= 1) a += __shfl_down(a, o, 64);
    if (threadIdx.x == 0) cbdp[0] = a;
  }
}

// weight split: m 0..1 -> hi+lo, m 2..3 -> hi only (4096x1024 fp32 each)
__global__ void k_wsplit(const float* __restrict__ w1ih, const float* __restrict__ w1hh,
                         const float* __restrict__ w2ih, const float* __restrict__ w2hh,
                         bf16* __restrict__ o1ih_h, bf16* __restrict__ o1ih_l,
                         bf16* __restrict__ o1hh_h, bf16* __restrict__ o1hh_l,
                         bf16* __restrict__ o2ih_h, bf16* __restrict__ o2hh_h)
{
  const int m = blockIdx.x >> 12;
  const size_t i4 = (size_t)(blockIdx.x & 4095) * 256 + threadIdx.x;
  const float* src = (m == 0) ? w1ih : (m == 1) ? w1hh : (m == 2) ? w2ih : w2hh;
  bf16* dh = (m == 0) ? o1ih_h : (m == 1) ? o1hh_h : (m == 2) ? o2ih_h : o2hh_h;
  bf16* dl = (m == 0) ? o1ih_l : (m == 1) ? o1hh_l : nullptr;
  f32x4 v = *(const f32x4*)(src + i4 * 4);
  short4v hv, lv;
#pragma unroll
  for (int j = 0; j < 4; ++j) {
    float x = v[j];
    bf16 h = __float2bfloat16(x);
    hv[j] = __builtin_bit_cast(short, h);
    lv[j] = bfbits(x - __bfloat162float(h));
  }
  *(short4v*)((short*)dh + i4 * 4) = hv;
  if (dl) *(short4v*)((short*)dl + i4 * 4) = lv;
}

// ---------------------------------------------------------------------------
// embed: v = relu(video@Wemb^T+bemb) fp32 into 8-slot chunk buffer.
// grid 64 = 8 bt x 8 ct; tile row r: b = bt*16+(r>>3), t = c*8+(r&7).
// vx row = (t&7)*128 + b. 3 passes (AhBh, AlBh, AhBl).
// ---------------------------------------------------------------------------
__global__ __launch_bounds__(256, 2) void k_embed(
    const float* __restrict__ video, const float* __restrict__ Wemb,
    const float* __restrict__ bemb, float* __restrict__ vx, int c)
{
  __shared__ __align__(16) short ls[16384];
  const int bt = (blockIdx.x >> 3) & 7;
  const int ct = blockIdx.x & 7;
  const int tid = threadIdx.x;

  int srow[4], sseg[4], ssw[4];
  const float* arow[4];
  const float* brow[4];
#pragma unroll
  for (int i = 0; i < 4; ++i) {
    int linear = i * 256 + tid;
    srow[i] = linear >> 3;
    sseg[i] = linear & 7;
    ssw[i]  = (sseg[i] ^ (srow[i] & 7)) * 8;
    int b = bt * 16 + (srow[i] >> 3);
    int t = c * 8 + (srow[i] & 7);
    arow[i] = video + (size_t)(b * 64 + t) * 2048 + sseg[i] * 8;
    brow[i] = Wemb + (size_t)(ct * 128 + srow[i]) * 2048 + sseg[i] * 8;
  }

  f32x4 acc[4][4] = {};
  const int lane = tid & 63, wave = tid >> 6;
  const int wr = (wave & 1) * 64, wc = (wave >> 1) * 64;
  const int m = lane & 15, kg = lane >> 4;

  for (int pass = 0; pass < 3; ++pass) {
    const int amode = (pass == 1), bmode = (pass == 2);
    for (int cc = 0; cc < 32; ++cc) {
#pragma unroll
      for (int i = 0; i < 4; ++i) {
        *(short8*)(ls + srow[i] * 64 + ssw[i])        = cvt8(arow[i] + cc * 64, amode);
        *(short8*)(ls + 8192 + srow[i] * 64 + ssw[i]) = cvt8(brow[i] + cc * 64, bmode);
      }
      __syncthreads();
#pragma unroll
      for (int ks = 0; ks < 2; ++ks) {
        short8 af[4], bfr[4];
#pragma unroll
        for (int f = 0; f < 4; ++f) {
          int ar = wr + f * 16 + m;
          af[f]  = *(const short8*)(ls + ar * 64 + (((ks * 4 + kg) ^ (ar & 7)) * 8));
          int br = wc + f * 16 + m;
          bfr[f] = *(const short8*)(ls + 8192 + br * 64 + (((ks * 4 + kg) ^ (br & 7)) * 8));
        }
#pragma unroll
        for (int fr = 0; fr < 4; ++fr)
#pragma unroll
          for (int fc = 0; fc < 4; ++fc)
            acc[fr][fc] = __builtin_amdgcn_mfma_f32_16x16x32_bf16(af[fr], bfr[fc], acc[fr][fc], 0, 0, 0);
      }
      __syncthreads();
    }
  }

  epilogue(acc, [&](int lrow, int lcol, float aval) {
    int b  = bt * 16 + (lrow >> 3);
    int t  = c * 8 + (lrow & 7);
    int gcol = ct * 128 + lcol;
    float x = fmaxf(aval + bemb[gcol], 0.0f);
    vx[(size_t)((t & 7) * 128 + b) * 1024 + gcol] = x;
  });
}

// zx chunk (fp64): zx[c*1024+rr] = vx[rr,:].u + cbd
__global__ void k_zx(const float* __restrict__ vx, const double* __restrict__ u,
                     const double* __restrict__ cbdp, float* __restrict__ zx, int c)
{
  const int wave = blockIdx.x * 4 + (threadIdx.x >> 6);
  const int lane = threadIdx.x & 63;
  for (int it = 0; it < 16; ++it) {
    int rr = wave * 16 + it;
    double a = 0.0;
#pragma unroll
    for (int q = 0; q < 16; ++q) {
      int h = lane + q * 64;
      a += (double)vx[(size_t)rr * 1024 + h] * u[h];
    }
#pragma unroll
    for (int o = 32; o > 0; o >>= 1) a += __shfl_down(a, o, 64);
    if (lane == 0) zx[c * 1024 + rr] = (float)(a + cbdp[0]);
  }
}

// ---------------------------------------------------------------------------
// G_k: grid 128 = 4 ops x 32 ct. R = [RA_x RA_h RB_x RB_h] fp32 (128x4096 ea).
// ---------------------------------------------------------------------------
__global__ __launch_bounds__(256, 2) void k_step(
    const float* __restrict__ vx,
    const bf16* __restrict__ h1r1h, const bf16* __restrict__ h1r1l,
    const bf16* __restrict__ h1r2h, const bf16* __restrict__ h1r2l,
    const bf16* __restrict__ h2h, const bf16* __restrict__ h2l,
    const bf16* __restrict__ w1ih_h, const bf16* __restrict__ w1ih_l,
    const bf16* __restrict__ w1hh_h, const bf16* __restrict__ w1hh_l,
    const bf16* __restrict__ w2ih_h, const bf16* __restrict__ w2hh_h,
    float* __restrict__ R, int k)
{
  __shared__ __align__(16) short ls[32768];
  const int op = blockIdx.x >> 5;
  const int ct = blockIdx.x & 31;
  if (k == 64 && op < 2) return;   // E_64 only consumes RB

  f32x4 acc[4][4] = {};
  const size_t boff = (size_t)ct * 128 * 1024;
  if (op == 0) {
    const float* Af = vx + (size_t)(k & 7) * 131072;
    gemm_core(Af, nullptr, 1024, 0, w1ih_h + boff, 1024, 16, ls, acc);
    gemm_core(Af, nullptr, 1024, 1, w1ih_h + boff, 1024, 16, ls, acc);
    gemm_core(Af, nullptr, 1024, 0, w1ih_l + boff, 1024, 16, ls, acc);
  } else if (op == 1) {
    gemm_core(nullptr, h1r1h, 1024, 0, w1hh_h + boff, 1024, 16, ls, acc);
    gemm_core(nullptr, h1r1l, 1024, 0, w1hh_h + boff, 1024, 16, ls, acc);
    gemm_core(nullptr, h1r1h, 1024, 0, w1hh_l + boff, 1024, 16, ls, acc);
  } else if (op == 2) {
    gemm_core(nullptr, h1r2h, 1024, 0, w2ih_h + boff, 1024, 16, ls, acc);
    gemm_core(nullptr, h1r2l, 1024, 0, w2ih_h + boff, 1024, 16, ls, acc);
  } else {
    gemm_core(nullptr, h2h, 1024, 0, w2hh_h + boff, 1024, 16, ls, acc);
    gemm_core(nullptr, h2l, 1024, 0, w2hh_h + boff, 1024, 16, ls, acc);
  }
  float* Rout = R + (size_t)op * 524288;
  epilogue(acc, [&](int lrow, int lcol, float aval) {
    Rout[(size_t)lrow * 4096 + ct * 128 + lcol] = aval;
  });
}

// ---------------------------------------------------------------------------
// E_k: grid 64 x 256; block handles b in {2*blk, 2*blk+1} (128 threads each).
// ---------------------------------------------------------------------------
__global__ void k_elem(const float* __restrict__ R, const float* __restrict__ zx,
                       float* __restrict__ craw,
                       bf16* __restrict__ h1r1h, bf16* __restrict__ h1r1l,
                       bf16* __restrict__ h1r2h, bf16* __restrict__ h1r2l,
                       float* __restrict__ c2, bf16* __restrict__ h2h, bf16* __restrict__ h2l,
                       float* __restrict__ rdm2, const double* __restrict__ wv,
                       const float* __restrict__ b1, float* __restrict__ dout, int k)
{
  const int tid = threadIdx.x;
  const int b   = blockIdx.x * 2 + (tid >> 7);
  const int j0  = tid & 127;

  if (k < 64) {  // boundary gate + lstm1 step k
    float zpre = zx[k * 128 + b];
    if (k > 0)
      zpre += rdm2[((k - 1) * 128 + b) * 2] + rdm2[((k - 1) * 128 + b) * 2 + 1];
    float s  = (sigm(zpre) > 0.5f) ? 1.0f : 0.0f;  // round(): 0.5 -> 0
    float om = 1.0f - s;

    const float* ax = R + (size_t)b * 4096;
    const float* ah = R + 524288 + (size_t)b * 4096;
    double rd = 0.0;
#pragma unroll
    for (int ji = 0; ji < 8; ++ji) {
      int j = j0 + ji * 128;
      float gi = ax[j]        + ah[j]        + b1[j];
      float gf = ax[1024 + j] + ah[1024 + j] + b1[1024 + j];
      float gg = ax[2048 + j] + ah[2048 + j] + b1[2048 + j];
      float go = ax[3072 + j] + ah[3072 + j] + b1[3072 + j];
      float cn = sigm(gf) * craw[b * 1024 + j] + sigm(gi) * tanhf(gg);
      float hn = sigm(go) * tanhf(cn);
      craw[b * 1024 + j] = om * cn;
      float v1 = om * hn;
      bf16 h1 = __float2bfloat16(v1);
      h1r1h[b * 1024 + j] = h1;
      h1r1l[b * 1024 + j] = __float2bfloat16(v1 - __bfloat162float(h1));
      float v2 = s * hn;
      bf16 h2v = __float2bfloat16(v2);
      h1r2h[b * 1024 + j] = h2v;
      h1r2l[b * 1024 + j] = __float2bfloat16(v2 - __bfloat162float(h2v));
      rd += (double)hn * wv[j];
    }
#pragma unroll
    for (int o = 32; o > 0; o >>= 1) rd += __shfl_down(rd, o, 64);
    if ((tid & 63) == 0)
      rdm2[((size_t)k * 128 + b) * 2 + ((tid >> 6) & 1)] = om * (float)rd;
  }

  if (k >= 1) {  // lstm2 step k-1 (RB_x pre-masked by s_{k-1}; bias-free)
    const float* bx = R + 2 * 524288 + (size_t)b * 4096;
    const float* bh = R + 3 * 524288 + (size_t)b * 4096;
#pragma unroll
    for (int ji = 0; ji < 8; ++ji) {
      int j = j0 + ji * 128;
      float gi = bx[j]        + bh[j];
      float gf = bx[1024 + j] + bh[1024 + j];
      float gg = bx[2048 + j] + bh[2048 + j];
      float go = bx[3072 + j] + bh[3072 + j];
      float cn = sigm(gf) * c2[b * 1024 + j] + sigm(gi) * tanhf(gg);
      float hn = sigm(go) * tanhf(cn);
      c2[b * 1024 + j] = cn;
      bf16 hh = __float2bfloat16(hn);
      h2h[b * 1024 + j] = hh;
      h2l[b * 1024 + j] = __float2bfloat16(hn - __bfloat162float(hh));
      if (k == 64) dout[b * 1024 + j] = hn;   // FP32 output (reference dtype)
    }
  }
}

// ---------------------------------------------------------------------------
extern "C" void kernel_launch(void* const* d_in, const int* in_sizes, int n_in,
                              void* d_out, int out_size, void* d_ws, size_t ws_size,
                              hipStream_t stream) {
  const float* video = (const float*)d_in[0];
  const float* Wemb  = (const float*)d_in[1];
  const float* bemb  = (const float*)d_in[2];
  const float* Wih1  = (const float*)d_in[3];
  const float* Whh1  = (const float*)d_in[4];
  const float* b1    = (const float*)d_in[5];
  const float* Wsi   = (const float*)d_in[6];
  const float* Wsh   = (const float*)d_in[7];
  const float* bbd   = (const float*)d_in[8];
  const float* vs    = (const float*)d_in[9];
  const float* Wih2  = (const float*)d_in[10];
  const float* Whh2  = (const float*)d_in[11];
  float* dout = (float*)d_out;

  static const int exp_sizes[12] = {
    128 * 64 * 2048, 1024 * 2048, 1024, 4096 * 1024, 4096 * 1024, 4096,
    512 * 1024, 512 * 1024, 512, 512, 4096 * 1024, 4096 * 1024 };
  int bad = -1;
  if (n_in != 12) bad = 99;
  else if (out_size != 131072) bad = 98;
  else
    for (int i = 0; i < 12; ++i)
      if (in_sizes[i] != exp_sizes[i]) { bad = i; break; }
  if (bad >= 0) {
    k_diag<<<1, 64, 0, stream>>>(dout, 10000.0f + (float)bad);
    return;
  }

  char* ws = (char*)d_ws;
  size_t off = 0;
  auto alloc = [&](size_t bytes) {
    char* p = ws + off;
    off += (bytes + 255) & ~(size_t)255;
    return p;
  };
  // zero region (state), memset each launch
  bf16*  h1r1h = (bf16*)alloc(262144);
  bf16*  h1r1l = (bf16*)alloc(262144);
  bf16*  h1r2h = (bf16*)alloc(262144);
  bf16*  h1r2l = (bf16*)alloc(262144);
  bf16*  h2h   = (bf16*)alloc(262144);
  bf16*  h2l   = (bf16*)alloc(262144);
  float* c2    = (float*)alloc(524288);
  float* craw  = (float*)alloc(524288);
  const size_t zeroBytes = off;
  // rest (written before read every launch)
  double* u    = (double*)alloc(8192);
  double* wvv  = (double*)alloc(8192);
  double* cbdp = (double*)alloc(256);
  float* rdm2  = (float*)alloc(64 * 128 * 2 * 4);
  float* zx    = (float*)alloc(8192 * 4);
  bf16* w1ih_h = (bf16*)alloc(8388608);
  bf16* w1ih_l = (bf16*)alloc(8388608);
  bf16* w1hh_h = (bf16*)alloc(8388608);
  bf16* w1hh_l = (bf16*)alloc(8388608);
  bf16* w2ih_h = (bf16*)alloc(8388608);
  bf16* w2hh_h = (bf16*)alloc(8388608);
  float* R     = (float*)alloc(4 * 524288 * 4);
  float* vx    = (float*)alloc(8 * 131072 * 4);   // 8-slot fp32 v chunk
  const size_t need = off;                         // ~62.8 MB

  if (ws_size < need) {
    k_diag<<<1, 64, 0, stream>>>(dout, 100.0f + (float)(ws_size >> 20));
    return;
  }

  (void)hipMemsetAsync(d_ws, 0, zeroBytes, stream);
  k_uw<<<9, 256, 0, stream>>>(Wsi, Wsh, bbd, vs, u, wvv, cbdp);
  k_wsplit<<<16384, 256, 0, stream>>>(Wih1, Whh1, Wih2, Whh2,
                                      w1ih_h, w1ih_l, w1hh_h, w1hh_l, w2ih_h, w2hh_h);

  for (int k = 0; k <= 64; ++k) {
    if (k < 64 && (k & 7) == 0) {
      int c = k >> 3;
      k_embed<<<64, 256, 0, stream>>>(video, Wemb, bemb, vx, c);
      k_zx<<<16, 256, 0, stream>>>(vx, u, cbdp, zx, c);
    }
    k_step<<<128, 256, 0, stream>>>(vx, h1r1h, h1r1l, h1r2h, h1r2l, h2h, h2l,
                                    w1ih_h, w1ih_l, w1hh_h, w1hh_l, w2ih_h, w2hh_h,
                                    R, k);
    k_elem<<<64, 256, 0, stream>>>(R, zx, craw, h1r1h, h1r1l, h1r2h, h1r2l,
                                   c2, h2h, h2l, rdm2, wvv, b1, dout, k);
  }
}

// Round 9
// 3260.278 us; speedup vs baseline: 3.1463x; 3.1463x over previous
//
#include <hip/hip_runtime.h>
#include <hip/hip_bf16.h>
#include <math.h>

// EncoderRNN on MI355X. Inputs fp32, output fp32. PASSING since R8 (absmax
// 2.4e-4); this round: performance. Full-machine grids + prefetch pipelines.
//   k_uw: u/w/cbd (fp64). k_wsplit: W1 -> bf16 hi+lo, W2 -> hi.
//   k_embed (512 blocks, prefetch dbuf): v=relu(video@Wemb^T+bemb) -> bf16 hi/lo
//   k_zx: zx[t*128+b] = v.u + cbd (fp64)
//   scan k=0..64:
//     k_step (256 blocks, 320 units = 10 passes x 32 ct, each K=1024):
//       p0..2: RAx partials (vh@w1ih_h, vl@w1ih_h, vh@w1ih_l)
//       p3..5: RAh partials (h1r1 hi/lo vs w1hh hi/lo)   [h1r1=(1-s)h1n]
//       p6..7: RBx partials (h1r2 hi/lo @ w2ih_h)         [h1r2=s*h1n]
//       p8..9: RBh partials (h2 hi/lo @ w2hh_h)
//     k_elem (128 blocks, b=blockIdx): s_k, lstm1_k, lstm2_{k-1}; k==64 -> dout
// R = 10 partial buffers (128x4096 f32) summed in E (deterministic).
// ws: full-v path ~104 MB, 8-slot chunk fallback ~75 MB, else exfil 100+MB.

typedef __attribute__((ext_vector_type(8))) short short8;
typedef __attribute__((ext_vector_type(4))) short short4v;
typedef __attribute__((ext_vector_type(4))) float f32x4;
typedef __hip_bfloat16 bf16;

__device__ __forceinline__ float sigm(float x) { return 1.0f / (1.0f + expf(-x)); }
__device__ __forceinline__ short bfbits(float x) {
  bf16 h = __float2bfloat16(x);
  return __builtin_bit_cast(short, h);
}
// fp32 -> 8 bf16 (mode 0: hi, mode 1: residual lo)
__device__ __forceinline__ short8 cvt8(const float* __restrict__ p, int mode)
{
  f32x4 a = *(const f32x4*)p;
  f32x4 b = *(const f32x4*)(p + 4);
  short8 r;
#pragma unroll
  for (int j = 0; j < 8; ++j) {
    float x = (j < 4) ? a[j] : b[j - 4];
    if (mode) {
      bf16 h = __float2bfloat16(x);
      x = x - __bfloat162float(h);
    }
    r[j] = bfbits(x);
  }
  return r;
}

// ---------------------------------------------------------------------------
// 128x128 GEMM tile: C += A(128xK)*B(128xK)^T, bf16 sources, fp32 acc.
// Double-buffered XOR-swizzled LDS; 16x16x32 MFMA; 2x2 waves of 64x64.
// ---------------------------------------------------------------------------
__device__ __forceinline__ void gemm_bf16(
    const bf16* __restrict__ A, int lda,
    const bf16* __restrict__ B, int ldb,
    int nChunks, short* ls, f32x4 acc[4][4])
{
  const int tid  = threadIdx.x;
  const int lane = tid & 63;
  const int wave = tid >> 6;
  const int wr = (wave & 1) * 64;
  const int wc = (wave >> 1) * 64;
  const int m  = lane & 15;
  const int kg = lane >> 4;

  int srow[4], sseg[4], ssw[4];
#pragma unroll
  for (int i = 0; i < 4; ++i) {
    int linear = i * 256 + tid;
    srow[i] = linear >> 3;
    sseg[i] = linear & 7;
    ssw[i]  = (sseg[i] ^ (srow[i] & 7)) * 8;
  }

  short8 areg[4], breg[4];
#pragma unroll
  for (int i = 0; i < 4; ++i) {
    areg[i] = *(const short8*)(A + (size_t)srow[i] * lda + sseg[i] * 8);
    breg[i] = *(const short8*)(B + (size_t)srow[i] * ldb + sseg[i] * 8);
  }
#pragma unroll
  for (int i = 0; i < 4; ++i) {
    *(short8*)(ls + srow[i] * 64 + ssw[i])        = areg[i];
    *(short8*)(ls + 8192 + srow[i] * 64 + ssw[i]) = breg[i];
  }
  __syncthreads();

  for (int c = 0; c < nChunks; ++c) {
    if (c + 1 < nChunks) {
#pragma unroll
      for (int i = 0; i < 4; ++i) {
        areg[i] = *(const short8*)(A + (size_t)srow[i] * lda + (c + 1) * 64 + sseg[i] * 8);
        breg[i] = *(const short8*)(B + (size_t)srow[i] * ldb + (c + 1) * 64 + sseg[i] * 8);
      }
    }
    const short* la = ls + (c & 1) * 16384;
    const short* lb = la + 8192;
#pragma unroll
    for (int ks = 0; ks < 2; ++ks) {
      short8 af[4], bfr[4];
#pragma unroll
      for (int f = 0; f < 4; ++f) {
        int ar = wr + f * 16 + m;
        af[f]  = *(const short8*)(la + ar * 64 + (((ks * 4 + kg) ^ (ar & 7)) * 8));
        int br = wc + f * 16 + m;
        bfr[f] = *(const short8*)(lb + br * 64 + (((ks * 4 + kg) ^ (br & 7)) * 8));
      }
#pragma unroll
      for (int fr = 0; fr < 4; ++fr)
#pragma unroll
        for (int fc = 0; fc < 4; ++fc)
          acc[fr][fc] = __builtin_amdgcn_mfma_f32_16x16x32_bf16(af[fr], bfr[fc], acc[fr][fc], 0, 0, 0);
    }
    if (c + 1 < nChunks) {
      short* lw = ls + ((c + 1) & 1) * 16384;
#pragma unroll
      for (int i = 0; i < 4; ++i) {
        *(short8*)(lw + srow[i] * 64 + ssw[i])        = areg[i];
        *(short8*)(lw + 8192 + srow[i] * 64 + ssw[i]) = breg[i];
      }
    }
    __syncthreads();
  }
}

// C/D frag layout (m89/m91-verified): col = lane&15, row = (lane>>4)*4 + reg.
template <typename F>
__device__ __forceinline__ void epilogue(const f32x4 acc[4][4], F&& body)
{
  const int tid = threadIdx.x, lane = tid & 63, wave = tid >> 6;
  const int m = lane & 15, kg = lane >> 4;
  const int wr = (wave & 1) * 64, wc = (wave >> 1) * 64;
#pragma unroll
  for (int fr = 0; fr < 4; ++fr)
#pragma unroll
    for (int fc = 0; fc < 4; ++fc)
#pragma unroll
      for (int r = 0; r < 4; ++r)
        body(wr + fr * 16 + kg * 4 + r, wc + fc * 16 + m, acc[fr][fc][r]);
}

// ---------------------------------------------------------------------------
__global__ void k_diag(float* __restrict__ out, float val)
{
  if (threadIdx.x == 0 && blockIdx.x == 0) out[0] = val;
}

// u[h]=sum_m vs[m]*Wsi[m,h]; w[h]=sum_m vs[m]*Wsh[m,h]; cbd=b_bd.vs (fp64)
__global__ void k_uw(const float* __restrict__ Wsi, const float* __restrict__ Wsh,
                     const float* __restrict__ bbd, const float* __restrict__ vs,
                     double* __restrict__ u, double* __restrict__ wv,
                     double* __restrict__ cbdp)
{
  const int blk = blockIdx.x;
  if (blk < 8) {
    const float* W = (blk < 4) ? Wsi : Wsh;
    double* out = (blk < 4) ? u : wv;
    int h = (blk & 3) * 256 + threadIdx.x;
    double a = 0.0;
    for (int mm = 0; mm < 512; ++mm)
      a += (double)vs[mm] * (double)W[mm * 1024 + h];
    out[h] = a;
  } else if (threadIdx.x < 64) {
    double a = 0.0;
    for (int mm = threadIdx.x; mm < 512; mm += 64)
      a += (double)vs[mm] * (double)bbd[mm];
#pragma unroll
    for (int o = 32; o > 0; o >>= 1) a += __shfl_down(a, o, 64);
    if (threadIdx.x == 0) cbdp[0] = a;
  }
}

// weight split: m 0..1 -> hi+lo, m 2..3 -> hi only (4096x1024 fp32 each)
__global__ void k_wsplit(const float* __restrict__ w1ih, const float* __restrict__ w1hh,
                         const float* __restrict__ w2ih, const float* __restrict__ w2hh,
                         bf16* __restrict__ o1ih_h, bf16* __restrict__ o1ih_l,
                         bf16* __restrict__ o1hh_h, bf16* __restrict__ o1hh_l,
                         bf16* __restrict__ o2ih_h, bf16* __restrict__ o2hh_h)
{
  const int m = blockIdx.x >> 12;
  const size_t i4 = (size_t)(blockIdx.x & 4095) * 256 + threadIdx.x;
  const float* src = (m == 0) ? w1ih : (m == 1) ? w1hh : (m == 2) ? w2ih : w2hh;
  bf16* dh = (m == 0) ? o1ih_h : (m == 1) ? o1hh_h : (m == 2) ? o2ih_h : o2hh_h;
  bf16* dl = (m == 0) ? o1ih_l : (m == 1) ? o1hh_l : nullptr;
  f32x4 v = *(const f32x4*)(src + i4 * 4);
  short4v hv, lv;
#pragma unroll
  for (int j = 0; j < 4; ++j) {
    float x = v[j];
    bf16 h = __float2bfloat16(x);
    hv[j] = __builtin_bit_cast(short, h);
    lv[j] = bfbits(x - __bfloat162float(h));
  }
  *(short4v*)((short*)dh + i4 * 4) = hv;
  if (dl) *(short4v*)((short*)dl + i4 * 4) = lv;
}

// ---------------------------------------------------------------------------
// embed: v = relu(video@Wemb^T+bemb) -> bf16 hi/lo. Block = (t, ct): rows are
// all 128 b for one t, cols ct*128..+128. 3 passes x 32 chunks, register-
// prefetch + double-buffered LDS (q = pass*32+chunk pipelined index).
// Output row (t & smask)*128 + b.
// ---------------------------------------------------------------------------
__global__ __launch_bounds__(256, 2) void k_embed(
    const float* __restrict__ video, const float* __restrict__ Wemb,
    const float* __restrict__ bemb, bf16* __restrict__ vhi, bf16* __restrict__ vlo,
    int tbase, int smask)
{
  __shared__ __align__(16) short ls[32768];   // 2 x (A 8192 + B 8192)
  const int t  = tbase + (blockIdx.x >> 3);
  const int ct = blockIdx.x & 7;
  const int tid = threadIdx.x;

  int srow[4], sseg[4], ssw[4];
  const float* arow[4];
  const float* brow[4];
#pragma unroll
  for (int i = 0; i < 4; ++i) {
    int linear = i * 256 + tid;
    srow[i] = linear >> 3;
    sseg[i] = linear & 7;
    ssw[i]  = (sseg[i] ^ (srow[i] & 7)) * 8;
    arow[i] = video + (size_t)(srow[i] * 64 + t) * 2048 + sseg[i] * 8;
    brow[i] = Wemb + (size_t)(ct * 128 + srow[i]) * 2048 + sseg[i] * 8;
  }

  f32x4 acc[4][4] = {};
  const int lane = tid & 63, wave = tid >> 6;
  const int wr = (wave & 1) * 64, wc = (wave >> 1) * 64;
  const int m = lane & 15, kg = lane >> 4;

  short8 areg[4], breg[4];
  // q = pass*32 + chunk; pass modes: p1 -> A lo, p2 -> B lo
#pragma unroll
  for (int i = 0; i < 4; ++i) {
    areg[i] = cvt8(arow[i], 0);
    breg[i] = cvt8(brow[i], 0);
  }
#pragma unroll
  for (int i = 0; i < 4; ++i) {
    *(short8*)(ls + srow[i] * 64 + ssw[i])        = areg[i];
    *(short8*)(ls + 8192 + srow[i] * 64 + ssw[i]) = breg[i];
  }
  __syncthreads();

  for (int q = 0; q < 96; ++q) {
    if (q + 1 < 96) {
      int pn = (q + 1) >> 5, cn = (q + 1) & 31;
      int am = (pn == 1), bm = (pn == 2);
#pragma unroll
      for (int i = 0; i < 4; ++i) {
        areg[i] = cvt8(arow[i] + cn * 64, am);
        breg[i] = cvt8(brow[i] + cn * 64, bm);
      }
    }
    const short* la = ls + (q & 1) * 16384;
    const short* lb = la + 8192;
#pragma unroll
    for (int ks = 0; ks < 2; ++ks) {
      short8 af[4], bfr[4];
#pragma unroll
      for (int f = 0; f < 4; ++f) {
        int ar = wr + f * 16 + m;
        af[f]  = *(const short8*)(la + ar * 64 + (((ks * 4 + kg) ^ (ar & 7)) * 8));
        int br = wc + f * 16 + m;
        bfr[f] = *(const short8*)(lb + br * 64 + (((ks * 4 + kg) ^ (br & 7)) * 8));
      }
#pragma unroll
      for (int fr = 0; fr < 4; ++fr)
#pragma unroll
        for (int fc = 0; fc < 4; ++fc)
          acc[fr][fc] = __builtin_amdgcn_mfma_f32_16x16x32_bf16(af[fr], bfr[fc], acc[fr][fc], 0, 0, 0);
    }
    if (q + 1 < 96) {
      short* lw = ls + ((q + 1) & 1) * 16384;
#pragma unroll
      for (int i = 0; i < 4; ++i) {
        *(short8*)(lw + srow[i] * 64 + ssw[i])        = areg[i];
        *(short8*)(lw + 8192 + srow[i] * 64 + ssw[i]) = breg[i];
      }
    }
    __syncthreads();
  }

  const int trow = (t & smask) * 128;
  epilogue(acc, [&](int lrow, int lcol, float aval) {
    int gcol = ct * 128 + lcol;
    float x = fmaxf(aval + bemb[gcol], 0.0f);
    bf16 hi = __float2bfloat16(x);
    size_t o = (size_t)(trow + lrow) * 1024 + gcol;
    vhi[o] = hi;
    vlo[o] = __float2bfloat16(x - __bfloat162float(hi));
  });
}

// zx (fp64): zx[base+rr] = (vhi+vlo)[rr,:] . u + cbd. rows = gridDim*4*16.
__global__ void k_zx(const bf16* __restrict__ vhi, const bf16* __restrict__ vlo,
                     const double* __restrict__ u, const double* __restrict__ cbdp,
                     float* __restrict__ zx, int base)
{
  const int wave = blockIdx.x * 4 + (threadIdx.x >> 6);
  const int lane = threadIdx.x & 63;
  for (int it = 0; it < 16; ++it) {
    int rr = wave * 16 + it;
    double a = 0.0;
#pragma unroll
    for (int q = 0; q < 16; ++q) {
      int h = lane + q * 64;
      size_t o = (size_t)rr * 1024 + h;
      a += (double)(__bfloat162float(vhi[o]) + __bfloat162float(vlo[o])) * u[h];
    }
#pragma unroll
    for (int o = 32; o > 0; o >>= 1) a += __shfl_down(a, o, 64);
    if (lane == 0) zx[base + rr] = (float)(a + cbdp[0]);
  }
}

// ---------------------------------------------------------------------------
// G_k: grid 256, units u in [0,320): p = u>>5 (pass), ct = u&31.
// R partial layout: R + p*524288, row-major 128x4096.
// ---------------------------------------------------------------------------
__global__ __launch_bounds__(256, 2) void k_step(
    const bf16* __restrict__ vhi, const bf16* __restrict__ vlo,
    const bf16* __restrict__ h1r1h, const bf16* __restrict__ h1r1l,
    const bf16* __restrict__ h1r2h, const bf16* __restrict__ h1r2l,
    const bf16* __restrict__ h2h, const bf16* __restrict__ h2l,
    const bf16* __restrict__ w1ih_h, const bf16* __restrict__ w1ih_l,
    const bf16* __restrict__ w1hh_h, const bf16* __restrict__ w1hh_l,
    const bf16* __restrict__ w2ih_h, const bf16* __restrict__ w2hh_h,
    float* __restrict__ R, int k, int smask)
{
  __shared__ __align__(16) short ls[32768];
  const bf16* vh = vhi + (size_t)(k & smask) * 131072;
  const bf16* vl = vlo + (size_t)(k & smask) * 131072;

  for (int u = blockIdx.x; u < 320; u += 256) {
    const int p  = u >> 5;
    const int ct = u & 31;
    if (k == 64 && p < 6) continue;   // E_64 only consumes RB
    if (k == 0 && p >= 3) continue;   // h-states zero; E_0 reads only p0..2

    const bf16 *A, *B;
    switch (p) {
      case 0: A = vh;    B = w1ih_h; break;
      case 1: A = vl;    B = w1ih_h; break;
      case 2: A = vh;    B = w1ih_l; break;
      case 3: A = h1r1h; B = w1hh_h; break;
      case 4: A = h1r1l; B = w1hh_h; break;
      case 5: A = h1r1h; B = w1hh_l; break;
      case 6: A = h1r2h; B = w2ih_h; break;
      case 7: A = h1r2l; B = w2ih_h; break;
      case 8: A = h2h;   B = w2hh_h; break;
      default: A = h2l;  B = w2hh_h; break;
    }
    f32x4 acc[4][4] = {};
    gemm_bf16(A, 1024, B + (size_t)ct * 131072, 1024, 16, ls, acc);
    float* Rout = R + (size_t)p * 524288;
    epilogue(acc, [&](int lrow, int lcol, float aval) {
      Rout[(size_t)lrow * 4096 + ct * 128 + lcol] = aval;
    });
  }
}

// ---------------------------------------------------------------------------
// E_k: grid 128 (b = blockIdx), 256 threads, 4 j each.
// ---------------------------------------------------------------------------
__global__ void k_elem(const float* __restrict__ R, const float* __restrict__ zx,
                       float* __restrict__ craw,
                       bf16* __restrict__ h1r1h, bf16* __restrict__ h1r1l,
                       bf16* __restrict__ h1r2h, bf16* __restrict__ h1r2l,
                       float* __restrict__ c2, bf16* __restrict__ h2h, bf16* __restrict__ h2l,
                       float* __restrict__ rdm, const double* __restrict__ wv,
                       const float* __restrict__ b1, float* __restrict__ dout, int k)
{
  __shared__ double red[4];
  const int tid = threadIdx.x;
  const int b   = blockIdx.x;
  const size_t broff = (size_t)b * 4096;
  const float* P0 = R + broff;
  const float* P1 = P0 + 524288;
  const float* P2 = P0 + 2 * 524288;
  const float* P3 = P0 + 3 * 524288;
  const float* P4 = P0 + 4 * 524288;
  const float* P5 = P0 + 5 * 524288;
  const float* P6 = P0 + 6 * 524288;
  const float* P7 = P0 + 7 * 524288;
  const float* P8 = P0 + 8 * 524288;
  const float* P9 = P0 + 9 * 524288;

  if (k < 64) {  // boundary gate + lstm1 step k
    float zpre = zx[k * 128 + b];
    if (k > 0) zpre += rdm[(k - 1) * 128 + b];
    float s  = (sigm(zpre) > 0.5f) ? 1.0f : 0.0f;   // round(): 0.5 -> 0
    float om = 1.0f - s;

    double rd = 0.0;
#pragma unroll
    for (int ji = 0; ji < 4; ++ji) {
      int j = tid + ji * 256;
      float gi = P0[j]        + P1[j]        + P2[j]        + b1[j];
      float gf = P0[1024 + j] + P1[1024 + j] + P2[1024 + j] + b1[1024 + j];
      float gg = P0[2048 + j] + P1[2048 + j] + P2[2048 + j] + b1[2048 + j];
      float go = P0[3072 + j] + P1[3072 + j] + P2[3072 + j] + b1[3072 + j];
      if (k > 0) {
        gi += P3[j]        + P4[j]        + P5[j];
        gf += P3[1024 + j] + P4[1024 + j] + P5[1024 + j];
        gg += P3[2048 + j] + P4[2048 + j] + P5[2048 + j];
        go += P3[3072 + j] + P4[3072 + j] + P5[3072 + j];
      }
      float cn = sigm(gf) * craw[b * 1024 + j] + sigm(gi) * tanhf(gg);
      float hn = sigm(go) * tanhf(cn);
      craw[b * 1024 + j] = om * cn;
      float v1 = om * hn;
      bf16 h1 = __float2bfloat16(v1);
      h1r1h[b * 1024 + j] = h1;
      h1r1l[b * 1024 + j] = __float2bfloat16(v1 - __bfloat162float(h1));
      float v2 = s * hn;
      bf16 h2v = __float2bfloat16(v2);
      h1r2h[b * 1024 + j] = h2v;
      h1r2l[b * 1024 + j] = __float2bfloat16(v2 - __bfloat162float(h2v));
      rd += (double)hn * wv[j];
    }
#pragma unroll
    for (int o = 32; o > 0; o >>= 1) rd += __shfl_down(rd, o, 64);
    if ((tid & 63) == 0) red[tid >> 6] = rd;
    __syncthreads();
    if (tid == 0)
      rdm[k * 128 + b] = om * (float)(red[0] + red[1] + red[2] + red[3]);
  }

  if (k >= 1) {  // lstm2 step k-1 (RBx pre-masked by s_{k-1}; bias-free)
#pragma unroll
    for (int ji = 0; ji < 4; ++ji) {
      int j = tid + ji * 256;
      float gi = P6[j]        + P7[j]        + P8[j]        + P9[j];
      float gf = P6[1024 + j] + P7[1024 + j] + P8[1024 + j] + P9[1024 + j];
      float gg = P6[2048 + j] + P7[2048 + j] + P8[2048 + j] + P9[2048 + j];
      float go = P6[3072 + j] + P7[3072 + j] + P8[3072 + j] + P9[3072 + j];
      float cn = sigm(gf) * c2[b * 1024 + j] + sigm(gi) * tanhf(gg);
      float hn = sigm(go) * tanhf(cn);
      c2[b * 1024 + j] = cn;
      bf16 hh = __float2bfloat16(hn);
      h2h[b * 1024 + j] = hh;
      h2l[b * 1024 + j] = __float2bfloat16(hn - __bfloat162float(hh));
      if (k == 64) dout[b * 1024 + j] = hn;
    }
  }
}

// ---------------------------------------------------------------------------
extern "C" void kernel_launch(void* const* d_in, const int* in_sizes, int n_in,
                              void* d_out, int out_size, void* d_ws, size_t ws_size,
                              hipStream_t stream) {
  const float* video = (const float*)d_in[0];
  const float* Wemb  = (const float*)d_in[1];
  const float* bemb  = (const float*)d_in[2];
  const float* Wih1  = (const float*)d_in[3];
  const float* Whh1  = (const float*)d_in[4];
  const float* b1    = (const float*)d_in[5];
  const float* Wsi   = (const float*)d_in[6];
  const float* Wsh   = (const float*)d_in[7];
  const float* bbd   = (const float*)d_in[8];
  const float* vs    = (const float*)d_in[9];
  const float* Wih2  = (const float*)d_in[10];
  const float* Whh2  = (const float*)d_in[11];
  float* dout = (float*)d_out;

  static const int exp_sizes[12] = {
    128 * 64 * 2048, 1024 * 2048, 1024, 4096 * 1024, 4096 * 1024, 4096,
    512 * 1024, 512 * 1024, 512, 512, 4096 * 1024, 4096 * 1024 };
  int bad = -1;
  if (n_in != 12) bad = 99;
  else if (out_size != 131072) bad = 98;
  else
    for (int i = 0; i < 12; ++i)
      if (in_sizes[i] != exp_sizes[i]) { bad = i; break; }
  if (bad >= 0) {
    k_diag<<<1, 64, 0, stream>>>(dout, 10000.0f + (float)bad);
    return;
  }

  char* ws = (char*)d_ws;
  size_t off = 0;
  auto alloc = [&](size_t bytes) {
    char* p = ws + off;
    off += (bytes + 255) & ~(size_t)255;
    return p;
  };
  // zero region (state), memset each launch
  bf16*  h1r1h = (bf16*)alloc(262144);
  bf16*  h1r1l = (bf16*)alloc(262144);
  bf16*  h1r2h = (bf16*)alloc(262144);
  bf16*  h1r2l = (bf16*)alloc(262144);
  bf16*  h2h   = (bf16*)alloc(262144);
  bf16*  h2l   = (bf16*)alloc(262144);
  float* c2    = (float*)alloc(524288);
  float* craw  = (float*)alloc(524288);
  const size_t zeroBytes = off;
  // rest (written before read every launch)
  double* u    = (double*)alloc(8192);
  double* wvv  = (double*)alloc(8192);
  double* cbdp = (double*)alloc(256);
  float* rdm   = (float*)alloc(64 * 128 * 4);
  float* zx    = (float*)alloc(8192 * 4);
  bf16* w1ih_h = (bf16*)alloc(8388608);
  bf16* w1ih_l = (bf16*)alloc(8388608);
  bf16* w1hh_h = (bf16*)alloc(8388608);
  bf16* w1hh_l = (bf16*)alloc(8388608);
  bf16* w2ih_h = (bf16*)alloc(8388608);
  bf16* w2hh_h = (bf16*)alloc(8388608);
  float* R     = (float*)alloc(10 * 524288 * 4);   // 10 partials, 21 MB
  const size_t fixedBytes = off;

  const size_t need_small = fixedBytes + 2 * ((size_t)8 * 131072 * 2 + 256);
  const size_t need_full  = fixedBytes + 2 * ((size_t)64 * 131072 * 2 + 256);
  if (ws_size < need_small) {
    k_diag<<<1, 64, 0, stream>>>(dout, 100.0f + (float)(ws_size >> 20));
    return;
  }
  const bool fullv = (ws_size >= need_full);
  const int slots = fullv ? 64 : 8;
  const int smask = slots - 1;
  bf16* vhi = (bf16*)alloc((size_t)slots * 131072 * 2);
  bf16* vlo = (bf16*)alloc((size_t)slots * 131072 * 2);

  (void)hipMemsetAsync(d_ws, 0, zeroBytes, stream);
  k_uw<<<9, 256, 0, stream>>>(Wsi, Wsh, bbd, vs, u, wvv, cbdp);
  k_wsplit<<<16384, 256, 0, stream>>>(Wih1, Whh1, Wih2, Whh2,
                                      w1ih_h, w1ih_l, w1hh_h, w1hh_l, w2ih_h, w2hh_h);
  if (fullv) {
    k_embed<<<512, 256, 0, stream>>>(video, Wemb, bemb, vhi, vlo, 0, smask);
    k_zx<<<128, 256, 0, stream>>>(vhi, vlo, u, cbdp, zx, 0);
  }

  for (int k = 0; k <= 64; ++k) {
    if (!fullv && k < 64 && (k & 7) == 0) {
      k_embed<<<64, 256, 0, stream>>>(video, Wemb, bemb, vhi, vlo, k, smask);
      k_zx<<<16, 256, 0, stream>>>(vhi, vlo, u, cbdp, zx, k * 128);
    }
    k_step<<<256, 256, 0, stream>>>(vhi, vlo, h1r1h, h1r1l, h1r2h, h1r2l, h2h, h2l,
                                    w1ih_h, w1ih_l, w1hh_h, w1hh_l, w2ih_h, w2hh_h,
                                    R, k, smask);
    k_elem<<<128, 256, 0, stream>>>(R, zx, craw, h1r1h, h1r1l, h1r2h, h1r2l,
                                    c2, h2h, h2l, rdm, wvv, b1, dout, k);
  }
}